// Round 2
// baseline (693.524 us; speedup 1.0000x reference)
//
#include <hip/hip_runtime.h>
#include <hip/hip_bf16.h>

#define B_DIM 32
#define L_DIM 512
#define D_DIM 768
#define N_PROMPT 20
#define D4 (D_DIM / 4)             // 192 float4 per (b,l) row
#define SLICES 16                  // blocks per batch row
#define L_PER_SLICE (L_DIM / SLICES)  // 32 l-positions per block

// One fused kernel. Grid = B_DIM * SLICES blocks, 256 threads.
// Phase A: block redundantly computes the pad-rank scan for its row (ballot
//          per 64-chunk + 8-chunk prefix), ranks into LDS. Slice 0 also
//          writes the attention_mask output (float; d_out is a float buffer).
// Phase B: block copies its 32 x 192-float4 slice of the embeddings,
//          selecting prompt rows where rank is valid.
__global__ __launch_bounds__(256) void prompt_fused_kernel(
    const int* __restrict__ sids,
    const float4* __restrict__ embeds,
    const int* __restrict__ mask,
    const float4* __restrict__ prompts,
    float4* __restrict__ out_embeds,
    float* __restrict__ out_mask) {
    const int b = blockIdx.x >> 4;        // 0..31
    const int slice = blockIdx.x & (SLICES - 1);
    const int tid = threadIdx.x;          // 0..255
    const int lane = tid & 63;
    const int wave = tid >> 6;            // 0..3

    __shared__ short rank_s[L_DIM];
    __shared__ int chunk_cnt[8];

    const int row_off = b * L_DIM;

    // ---- Phase A: pad-rank scan over the 512-entry mask row ----
    const int l0 = wave * 64 + lane;          // chunks 0..3
    const int l1 = 256 + wave * 64 + lane;    // chunks 4..7
    const int m0 = mask[row_off + l0];
    const int m1 = mask[row_off + l1];
    const unsigned long long bal0 = __ballot(m0 == 0);
    const unsigned long long bal1 = __ballot(m1 == 0);
    if (lane == 0) {
        chunk_cnt[wave]     = __popcll(bal0);
        chunk_cnt[wave + 4] = __popcll(bal1);
    }
    __syncthreads();
    int base0 = 0, base1 = 0;
    #pragma unroll
    for (int j = 0; j < 8; ++j) {
        const int c = chunk_cnt[j];
        if (j < wave)     base0 += c;
        if (j < wave + 4) base1 += c;
    }
    const unsigned long long lower = (1ULL << lane) - 1ULL; // lane0 -> 0
    const int r0 = base0 + __popcll(bal0 & lower);
    const int r1 = base1 + __popcll(bal1 & lower);
    const bool t0 = (m0 == 0) && (r0 < N_PROMPT);
    const bool t1 = (m1 == 0) && (r1 < N_PROMPT);
    rank_s[l0] = t0 ? (short)r0 : (short)-1;
    rank_s[l1] = t1 ? (short)r1 : (short)-1;
    if (slice == 0) {
        out_mask[row_off + l0] = t0 ? 1.0f : (float)m0;
        out_mask[row_off + l1] = t1 ? 1.0f : (float)m1;
    }
    __syncthreads();

    // ---- Phase B: copy this block's slice of the embeddings ----
    const int sid = sids[b];
    const int l_base = slice * L_PER_SLICE;
    #pragma unroll 4
    for (int i = tid; i < L_PER_SLICE * D4; i += 256) {
        const int l_off = i / D4;             // 0..31 (magic-mul)
        const int d = i - l_off * D4;
        const int l = l_base + l_off;
        const int s = rank_s[l];
        const size_t out_idx = ((size_t)row_off + l) * (size_t)D4 + d;
        float4 v;
        if (s >= 0) {
            v = prompts[((size_t)sid * N_PROMPT + s) * (size_t)D4 + d];
        } else {
            v = embeds[out_idx];
        }
        out_embeds[out_idx] = v;
    }
}

extern "C" void kernel_launch(void* const* d_in, const int* in_sizes, int n_in,
                              void* d_out, int out_size, void* d_ws, size_t ws_size,
                              hipStream_t stream) {
    const int*   sids    = (const int*)d_in[0];     // [B] sample ids
    const float* embeds  = (const float*)d_in[1];   // [B,L,D]
    const int*   mask    = (const int*)d_in[2];     // [B,L]
    const float* prompts = (const float*)d_in[3];   // [N_SAMPLES, N_PROMPT, D]

    float* out_embeds = (float*)d_out;                               // [B,L,D]
    float* out_mask   = out_embeds + (size_t)B_DIM * L_DIM * D_DIM;  // [B,L]

    prompt_fused_kernel<<<B_DIM * SLICES, 256, 0, stream>>>(
        sids, (const float4*)embeds, mask, (const float4*)prompts,
        (float4*)out_embeds, out_mask);
}